// Round 6
// baseline (95726.648 us; speedup 1.0000x reference)
//
#include <hip/hip_runtime.h>
#include <stdint.h>

#define L4   250   // chase chunk length
#define GRP  50    // chunks per map-composition group

// ---------------------------------------------------------------------------
// One exact Viterbi value step, fully hand-scheduled.
// Lane i (replicated 4x across the wave) holds fv[i] in rotating reg FI.
// b_d = fl(FI + tr[i^d][i]); xor-butterfly (masks 8,7,3,1; slot pairing
// y = x^m) -> b0 = max_p fl(fv[p]+tr[i][p]); FO = b0 + feat; store FO.
// DPP hazard distances (VALU write -> DPP-src read) all >= 3 (audited).
// Rotating FO regs (16-deep) make each store's data register live for a
// full batch; the batch-level s_waitcnt vmcnt(16) retires the store before
// its register is redefined. This is the manual version of what the
// compiler's SSA renaming + waitcnts did in R3/R4 -- minus the load-sinking.
// ---------------------------------------------------------------------------
#define ST1(FN, OFF, FI, FO) \
  "v_add_f32 %[b8],  %[t8],  %[" #FI "]\n\t" \
  "v_add_f32 %[b9],  %[t9],  %[" #FI "]\n\t" \
  "v_add_f32 %[b10], %[t10], %[" #FI "]\n\t" \
  "v_add_f32 %[b11], %[t11], %[" #FI "]\n\t" \
  "v_add_f32 %[b12], %[t12], %[" #FI "]\n\t" \
  "v_add_f32 %[b13], %[t13], %[" #FI "]\n\t" \
  "v_add_f32 %[b14], %[t14], %[" #FI "]\n\t" \
  "v_add_f32 %[b15], %[t15], %[" #FI "]\n\t" \
  "v_add_f32 %[b1],  %[t1],  %[" #FI "]\n\t" \
  "v_add_f32 %[b2],  %[t2],  %[" #FI "]\n\t" \
  "v_add_f32 %[b3],  %[t3],  %[" #FI "]\n\t" \
  "v_add_f32 %[b4],  %[t4],  %[" #FI "]\n\t" \
  "v_add_f32 %[b5],  %[t5],  %[" #FI "]\n\t" \
  "v_add_f32 %[b6],  %[t6],  %[" #FI "]\n\t" \
  "v_add_f32 %[b7],  %[t7],  %[" #FI "]\n\t" \
  "v_add_f32 %[b0],  %[t0],  %[" #FI "]\n\t" \
  "v_max_f32_dpp %[b0], %[b8],  %[b0] row_ror:8 row_mask:0xf bank_mask:0xf\n\t" \
  "v_max_f32_dpp %[b1], %[b9],  %[b1] row_ror:8 row_mask:0xf bank_mask:0xf\n\t" \
  "v_max_f32_dpp %[b2], %[b10], %[b2] row_ror:8 row_mask:0xf bank_mask:0xf\n\t" \
  "v_max_f32_dpp %[b3], %[b11], %[b3] row_ror:8 row_mask:0xf bank_mask:0xf\n\t" \
  "v_max_f32_dpp %[b4], %[b12], %[b4] row_ror:8 row_mask:0xf bank_mask:0xf\n\t" \
  "v_max_f32_dpp %[b5], %[b13], %[b5] row_ror:8 row_mask:0xf bank_mask:0xf\n\t" \
  "v_max_f32_dpp %[b6], %[b14], %[b6] row_ror:8 row_mask:0xf bank_mask:0xf\n\t" \
  "v_max_f32_dpp %[b7], %[b15], %[b7] row_ror:8 row_mask:0xf bank_mask:0xf\n\t" \
  "v_max_f32_dpp %[b3], %[b4], %[b3] row_half_mirror row_mask:0xf bank_mask:0xf\n\t" \
  "v_max_f32_dpp %[b2], %[b5], %[b2] row_half_mirror row_mask:0xf bank_mask:0xf\n\t" \
  "v_max_f32_dpp %[b1], %[b6], %[b1] row_half_mirror row_mask:0xf bank_mask:0xf\n\t" \
  "v_max_f32_dpp %[b0], %[b7], %[b0] row_half_mirror row_mask:0xf bank_mask:0xf\n\t" \
  "v_max_f32_dpp %[b1], %[b2], %[b1] quad_perm:[3,2,1,0] row_mask:0xf bank_mask:0xf\n\t" \
  "v_max_f32_dpp %[b0], %[b3], %[b0] quad_perm:[3,2,1,0] row_mask:0xf bank_mask:0xf\n\t" \
  "s_nop 0\n\t" \
  "v_max_f32_dpp %[b0], %[b1], %[b0] quad_perm:[1,0,3,2] row_mask:0xf bank_mask:0xf\n\t" \
  "v_add_f32 %[" #FO "], %[" #FN "], %[b0]\n\t" \
  "global_store_dword %[st], %[" #FO "], off offset:" #OFF "\n\t"

// 8-step bodies (lo: steps 0-7, hi: steps 8-15) for buffer prefix P (fa/fb).
#define LO8(P) \
  ST1(P##0,0,fv15,fv0)   ST1(P##1,64,fv0,fv1)   ST1(P##2,128,fv1,fv2) \
  ST1(P##3,192,fv2,fv3)  ST1(P##4,256,fv3,fv4)  ST1(P##5,320,fv4,fv5) \
  ST1(P##6,384,fv5,fv6)  ST1(P##7,448,fv6,fv7)
#define HI8(P) \
  ST1(P##8,512,fv7,fv8)  ST1(P##9,576,fv8,fv9)  ST1(P##10,640,fv9,fv10) \
  ST1(P##11,704,fv10,fv11) ST1(P##12,768,fv11,fv12) ST1(P##13,832,fv12,fv13) \
  ST1(P##14,896,fv13,fv14) ST1(P##15,960,fv14,fv15)

#define CB  [b0]"+v"(b0),[b1]"+v"(b1),[b2]"+v"(b2),[b3]"+v"(b3), \
            [b4]"+v"(b4),[b5]"+v"(b5),[b6]"+v"(b6),[b7]"+v"(b7), \
            [b8]"+v"(b8),[b9]"+v"(b9),[b10]"+v"(b10),[b11]"+v"(b11), \
            [b12]"+v"(b12),[b13]"+v"(b13),[b14]"+v"(b14),[b15]"+v"(b15)
#define CT  [t0]"v"(tr0),[t1]"v"(tr1),[t2]"v"(tr2),[t3]"v"(tr3), \
            [t4]"v"(tr4),[t5]"v"(tr5),[t6]"v"(tr6),[t7]"v"(tr7), \
            [t8]"v"(tr8),[t9]"v"(tr9),[t10]"v"(tr10),[t11]"v"(tr11), \
            [t12]"v"(tr12),[t13]"v"(tr13),[t14]"v"(tr14),[t15]"v"(tr15)

#define STEPS_LO(P) \
  asm volatile(LO8(P) \
    : CB, [fv0]"+v"(fv0),[fv1]"+v"(fv1),[fv2]"+v"(fv2),[fv3]"+v"(fv3), \
      [fv4]"+v"(fv4),[fv5]"+v"(fv5),[fv6]"+v"(fv6),[fv7]"+v"(fv7) \
    : CT, [fv15]"v"(fv15), [st]"v"(st), \
      [P##0]"v"(P##0),[P##1]"v"(P##1),[P##2]"v"(P##2),[P##3]"v"(P##3), \
      [P##4]"v"(P##4),[P##5]"v"(P##5),[P##6]"v"(P##6),[P##7]"v"(P##7) \
    : "memory")
#define STEPS_HI(P) \
  asm volatile(HI8(P) \
    : CB, [fv8]"+v"(fv8),[fv9]"+v"(fv9),[fv10]"+v"(fv10),[fv11]"+v"(fv11), \
      [fv12]"+v"(fv12),[fv13]"+v"(fv13),[fv14]"+v"(fv14),[fv15]"+v"(fv15) \
    : CT, [fv7]"v"(fv7), [st]"v"(st), \
      [P##8]"v"(P##8),[P##9]"v"(P##9),[P##10]"v"(P##10),[P##11]"v"(P##11), \
      [P##12]"v"(P##12),[P##13]"v"(P##13),[P##14]"v"(P##14),[P##15]"v"(P##15) \
    : "memory")

// Batched 16-load prefetch into buffer P (pure outputs, early-clobber).
#define LOAD16(P) \
  asm volatile( \
    "global_load_dword %[" #P "0],  %[pf], off\n\t" \
    "global_load_dword %[" #P "1],  %[pf], off offset:64\n\t" \
    "global_load_dword %[" #P "2],  %[pf], off offset:128\n\t" \
    "global_load_dword %[" #P "3],  %[pf], off offset:192\n\t" \
    "global_load_dword %[" #P "4],  %[pf], off offset:256\n\t" \
    "global_load_dword %[" #P "5],  %[pf], off offset:320\n\t" \
    "global_load_dword %[" #P "6],  %[pf], off offset:384\n\t" \
    "global_load_dword %[" #P "7],  %[pf], off offset:448\n\t" \
    "global_load_dword %[" #P "8],  %[pf], off offset:512\n\t" \
    "global_load_dword %[" #P "9],  %[pf], off offset:576\n\t" \
    "global_load_dword %[" #P "10], %[pf], off offset:640\n\t" \
    "global_load_dword %[" #P "11], %[pf], off offset:704\n\t" \
    "global_load_dword %[" #P "12], %[pf], off offset:768\n\t" \
    "global_load_dword %[" #P "13], %[pf], off offset:832\n\t" \
    "global_load_dword %[" #P "14], %[pf], off offset:896\n\t" \
    "global_load_dword %[" #P "15], %[pf], off offset:960\n\t" \
    : [P##0]"=&v"(P##0),[P##1]"=&v"(P##1),[P##2]"=&v"(P##2),[P##3]"=&v"(P##3), \
      [P##4]"=&v"(P##4),[P##5]"=&v"(P##5),[P##6]"=&v"(P##6),[P##7]"=&v"(P##7), \
      [P##8]"=&v"(P##8),[P##9]"=&v"(P##9),[P##10]"=&v"(P##10),[P##11]"=&v"(P##11), \
      [P##12]"=&v"(P##12),[P##13]"=&v"(P##13),[P##14]"=&v"(P##14),[P##15]"=&v"(P##15) \
    : [pf]"v"(pf) : "memory")

#define W16 asm volatile("s_waitcnt vmcnt(16)" ::: "memory")
#define W0  asm volatile("s_waitcnt vmcnt(0)"  ::: "memory")

// ---------------------------------------------------------------------------
// K1: value-only exact Viterbi forward chain. ONE wave, fully hand-scheduled
// asm hot loop with manual vmcnt double-buffering (compiler was sinking the
// source-level prefetch to the use point -> ~200cyc L2 latency per step).
// ---------------------------------------------------------------------------
__global__ __launch_bounds__(64, 1)
void k_chain(const float* __restrict__ feats, const float* __restrict__ trans,
             float* __restrict__ FV, int* __restrict__ last_tag, int T) {
  const int l = threadIdx.x;
  const int i = l & 15;

  const float tr0  = trans[((i ^ 0)  << 4) + i];
  const float tr1  = trans[((i ^ 1)  << 4) + i];
  const float tr2  = trans[((i ^ 2)  << 4) + i];
  const float tr3  = trans[((i ^ 3)  << 4) + i];
  const float tr4  = trans[((i ^ 4)  << 4) + i];
  const float tr5  = trans[((i ^ 5)  << 4) + i];
  const float tr6  = trans[((i ^ 6)  << 4) + i];
  const float tr7  = trans[((i ^ 7)  << 4) + i];
  const float tr8  = trans[((i ^ 8)  << 4) + i];
  const float tr9  = trans[((i ^ 9)  << 4) + i];
  const float tr10 = trans[((i ^ 10) << 4) + i];
  const float tr11 = trans[((i ^ 11) << 4) + i];
  const float tr12 = trans[((i ^ 12) << 4) + i];
  const float tr13 = trans[((i ^ 13) << 4) + i];
  const float tr14 = trans[((i ^ 14) << 4) + i];
  const float tr15 = trans[((i ^ 15) << 4) + i];

  float b0=0,b1=0,b2=0,b3=0,b4=0,b5=0,b6=0,b7=0;
  float b8=0,b9=0,b10=0,b11=0,b12=0,b13=0,b14=0,b15=0;
  float fv0=0,fv1=0,fv2=0,fv3=0,fv4=0,fv5=0,fv6=0,fv7=0;
  float fv8=0,fv9=0,fv10=0,fv11=0,fv12=0,fv13=0,fv14=0,fv15=0; // fv15 = fv carry, init 0
  float fa0=0,fa1=0,fa2=0,fa3=0,fa4=0,fa5=0,fa6=0,fa7=0;
  float fa8=0,fa9=0,fa10=0,fa11=0,fa12=0,fa13=0,fa14=0,fa15=0;
  float fb0=0,fb1=0,fb2=0,fb3=0,fb4=0,fb5=0,fb6=0,fb7=0;
  float fb8=0,fb9=0,fb10=0,fb11=0,fb12=0,fb13=0,fb14=0,fb15=0;

  FV[i] = 0.0f;  // FV[0] = init_fv = zeros (before all asm; "memory" orders)

  const int NB  = T / 16;
  const int rem = T % 16;
  uint64_t pf = (uint64_t)(feats + i);       // per-lane feat addr
  uint64_t st = (uint64_t)(FV + 16 + i);     // per-lane FV[t+1] addr

  if (NB >= 1) {
    LOAD16(fa); pf += 1024;                  // preload batch 0
    for (int h = 0; h < NB - 1; ++h) {
      if ((h & 1) == 0) { LOAD16(fb); W16; STEPS_LO(fa); STEPS_HI(fa); }
      else              { LOAD16(fa); W16; STEPS_LO(fb); STEPS_HI(fb); }
      pf += 1024; st += 1024;
    }
    W0;                                      // retire last loads + stores
    if (((NB - 1) & 1) == 0) { STEPS_LO(fa); STEPS_HI(fa); }
    else                     { STEPS_LO(fb); STEPS_HI(fb); }
    st += 1024;
  }
  for (int t = NB * 16; t < T; ++t) {        // tail (T%16 steps)
    float ftv = feats[(size_t)t * 16 + i];
    asm volatile(ST1(ft, 0, fv15, fv14)
      : CB, [fv14]"+v"(fv14)
      : CT, [fv15]"v"(fv15), [ft]"v"(ftv), [st]"v"(st)
      : "memory");
    W0;
    fv15 = fv14;
    st += 64;
  }
  (void)rem;
  W0;

  // last_tag = argmax (first-index tie-break) of final fv (in fv15)
  float bv = __shfl(fv15, 0, 64); int bi = 0;
  #pragma unroll
  for (int p = 1; p < 16; ++p) {
    float ov = __shfl(fv15, p, 64);
    if (ov > bv) { bv = ov; bi = p; }
  }
  if (l == 0) *last_tag = bi;
}

// ---------------------------------------------------------------------------
// K2: parallel backpointer recompute. Thread per t. Bit-identical argmax
// (strict >, first-index) from exact FV[t].
// ---------------------------------------------------------------------------
__global__ __launch_bounds__(256)
void k_bp(const float* __restrict__ FV, const float* __restrict__ trans,
          uint4* __restrict__ bp, int T) {
  __shared__ float str[256];
  const int tid = threadIdx.x;
  str[tid] = trans[tid];
  __syncthreads();
  const int t = blockIdx.x * blockDim.x + tid;
  if (t >= T) return;
  const float4* fr = (const float4*)(FV + (size_t)t * 16);
  float4 q0 = fr[0], q1 = fr[1], q2 = fr[2], q3 = fr[3];
  float fv[16] = {q0.x, q0.y, q0.z, q0.w, q1.x, q1.y, q1.z, q1.w,
                  q2.x, q2.y, q2.z, q2.w, q3.x, q3.y, q3.z, q3.w};
  uint32_t w[4];
  #pragma unroll
  for (int g = 0; g < 4; ++g) {
    uint32_t word = 0;
    #pragma unroll
    for (int s = 0; s < 4; ++s) {
      const int nn = 4 * g + s;
      float best = fv[0] + str[nn * 16 + 0];
      int bi = 0;
      #pragma unroll
      for (int p = 1; p < 16; ++p) {
        float v = fv[p] + str[nn * 16 + p];
        if (v > best) { best = v; bi = p; }
      }
      word |= (uint32_t)bi << (8 * s);
    }
    w[g] = word;
  }
  bp[t] = make_uint4(w[0], w[1], w[2], w[3]);
}

// ---------------------------------------------------------------------------
// K3: per-chunk 16-hypothesis backtrack (exact integer pointer chase).
// ---------------------------------------------------------------------------
__global__ __launch_bounds__(64)
void k_chase(const unsigned char* __restrict__ bp, unsigned char* __restrict__ st,
             unsigned char* __restrict__ maps, int T, int C) {
  const int tid = threadIdx.x;
  const int chunk = blockIdx.x * 4 + (tid >> 4);
  const int h = tid & 15;
  if (chunk >= C) return;
  const int a = chunk * L4;
  int b = a + L4; if (b > T) b = T;
  int cur = h;
  for (int t = b - 1; t >= a; --t) {
    cur = bp[(size_t)t * 16 + cur];
    st[(size_t)t * 16 + h] = (unsigned char)cur;
  }
  maps[chunk * 16 + h] = (unsigned char)cur;
}

// ---------------------------------------------------------------------------
// K4: compose GRP consecutive chunk maps into one super-map per group.
// ---------------------------------------------------------------------------
__global__ __launch_bounds__(64)
void k_group(const unsigned char* __restrict__ maps, unsigned char* __restrict__ sup,
             int C, int NG) {
  const int g = blockIdx.x;
  const int e = threadIdx.x;
  if (g >= NG || e >= 16) return;
  int hi = g * GRP + GRP - 1; if (hi > C - 1) hi = C - 1;
  int cur = e;
  for (int c = hi; c >= g * GRP; --c) cur = maps[c * 16 + cur];
  sup[g * 16 + e] = (unsigned char)cur;
}

// ---------------------------------------------------------------------------
// K5: resolve true tag at every chunk's end boundary.
// ---------------------------------------------------------------------------
__global__ __launch_bounds__(128)
void k_resolve(const unsigned char* __restrict__ maps, const unsigned char* __restrict__ sup,
               const int* __restrict__ last_tag, unsigned char* __restrict__ s_arr,
               int C, int NG) {
  __shared__ unsigned char Sg[4096];
  const int tid = threadIdx.x;
  if (tid == 0) {
    int cur = *last_tag;
    for (int g = NG - 1; g >= 0; --g) {
      Sg[g] = (unsigned char)cur;
      cur = sup[g * 16 + cur];
    }
  }
  __syncthreads();
  for (int g = tid; g < NG; g += blockDim.x) {
    int cur = Sg[g];
    int hi = g * GRP + GRP - 1; if (hi > C - 1) hi = C - 1;
    for (int c = hi; c >= g * GRP; --c) {
      s_arr[c] = (unsigned char)cur;
      cur = maps[c * 16 + cur];
    }
  }
}

// ---------------------------------------------------------------------------
// K6: emit out[t] = st[t*16 + s_arr[t / L4]] as int32.
// ---------------------------------------------------------------------------
__global__ void k_emit(const unsigned char* __restrict__ st,
                       const unsigned char* __restrict__ s_arr,
                       int* __restrict__ out, int T) {
  int t = blockIdx.x * blockDim.x + threadIdx.x;
  if (t < T) out[t] = (int)st[(size_t)t * 16 + s_arr[t / L4]];
}

extern "C" void kernel_launch(void* const* d_in, const int* in_sizes, int n_in,
                              void* d_out, int out_size, void* d_ws, size_t ws_size,
                              hipStream_t stream) {
  const float* feats = (const float*)d_in[0];   // [1, T, 16] fp32
  const float* trans = (const float*)d_in[1];   // [16, 16]  fp32
  int* out = (int*)d_out;                       // [T] int32

  const int T  = in_sizes[0] / 16;
  const int C  = (T + L4 - 1) / L4;
  const int NG = (C + GRP - 1) / GRP;

  char* ws = (char*)d_ws;
  float* FV           = (float*)ws;                                   // (T+1)*16 floats
  unsigned char* bp   = (unsigned char*)(FV + (size_t)(T + 1) * 16);  // T*16 B
  unsigned char* st   = bp + (size_t)T * 16;                          // T*16 B
  unsigned char* maps = st + (size_t)T * 16;                          // C*16
  unsigned char* sup  = maps + (size_t)C * 16;                        // NG*16
  unsigned char* sarr = sup + (size_t)NG * 16;                        // C
  int* last_tag = (int*)(((uintptr_t)(sarr + C) + 15) & ~(uintptr_t)15);
  size_t need = (size_t)((char*)(last_tag + 1) - ws);
  if (ws_size < need) return;  // insufficient scratch -> fail visibly

  k_chain<<<1, 64, 0, stream>>>(feats, trans, FV, last_tag, T);
  k_bp<<<(T + 255) / 256, 256, 0, stream>>>(FV, trans, (uint4*)bp, T);
  k_chase<<<(C + 3) / 4, 64, 0, stream>>>(bp, st, maps, T, C);
  k_group<<<NG, 64, 0, stream>>>(maps, sup, C, NG);
  k_resolve<<<1, 128, 0, stream>>>(maps, sup, last_tag, sarr, C, NG);
  const int thr = 256;
  k_emit<<<(T + thr - 1) / thr, thr, 0, stream>>>(st, sarr, out, T);
}